// Round 12
// baseline (159.751 us; speedup 1.0000x reference)
//
#include <hip/hip_runtime.h>

// Autoregressive LSTM log-prob — wave-private MFMA recurrence, barrier-free.
// B=4096, L=256, H=32, D=2. 2048 WGs x 64 threads: ONE wave owns TWO batches
// for the full 256-step recurrence. No __syncthreads anywhere; h round-trips
// through a 160 B single-buffer LDS region (same-wave DS ops are in-order).
// gates^T = Wh^T @ h^T: A = scaled weights (8 tiles: 4 gates x 2 unit-halves),
// B = h with batches in N-cols n = m + 2j. Lane (n,oct) owns cell
// u = 4*oct + (j&3) + 16*(j>>2) of batch m=n&1; its 4 gates are extracted
// from acc tiles (2q + (j>>2)), reg (j&3) via a 7-cndmask tree per gate.
// K-slot identity: B element jj <-> unit 8*oct+jj <-> hbuf[m][8*oct..].
// Gate scales folded (i,f,o: -log2e; g: +2log2e); bias added post-extract;
// cell state kept as c' = 2*log2e*c. Head = 9th MFMA (Wo^T rows 0,1) every
// step; t runs 1..256 with step 256 dead except its head (= step-255 logits).
// Spins packed as bits: 1 ds_read_b32 per 32 steps, static shifts.
// 8 independent waves/CU (2/SIMD) de-phase and fill each other's chain gaps.

typedef __attribute__((ext_vector_type(8))) short bf16x8;
typedef __attribute__((ext_vector_type(4))) float f32x4;

#define LOG2E  1.4426950408889634f
#define TWOL   2.8853900817779268f
#define LN2    0.6931471805599453f

__device__ __forceinline__ float fexp2(float x) { return __builtin_amdgcn_exp2f(x); }
__device__ __forceinline__ float flog2(float x) { return __builtin_amdgcn_logf(x); }
__device__ __forceinline__ float frcp(float x)  { return __builtin_amdgcn_rcpf(x); }

__device__ __forceinline__ float fsig(float x)   { return frcp(1.f + fexp2(-LOG2E * x)); }
__device__ __forceinline__ float ftanh_(float x) { return 1.f - 2.f * frcp(fexp2(TWOL * x) + 1.f); }
__device__ __forceinline__ float felu(float x)   { return x > 0.f ? x : fexp2(LOG2E * x) - 1.f; }

__device__ __forceinline__ unsigned short f2bf(float f) {   // RNE f32->bf16
    unsigned u = __builtin_bit_cast(unsigned, f);
    u = (u + 0x7FFFu + ((u >> 16) & 1u)) >> 16;
    return (unsigned short)u;
}

constexpr int Bsz = 4096;

__global__ __launch_bounds__(64, 2) void lstm_wpriv(
    const int*   __restrict__ x,    // [B, 256]
    const float* __restrict__ Wi,   // [2, 128]
    const float* __restrict__ Wh,   // [32, 128]
    const float* __restrict__ bh,   // [128]
    const float* __restrict__ Wo,   // [32, 2]
    const float* __restrict__ bo,   // [2]
    float*       __restrict__ out)  // [B]
{
    const int lane = threadIdx.x & 63;
    const int n    = lane & 15;     // N col
    const int oct  = lane >> 4;
    const int m    = n & 1;         // my batch (0/1)
    const int j    = n >> 1;        // cell selector 0..7
    const int b0   = blockIdx.x * 2;

    __shared__ unsigned spinw[2][8];   // [batch][word]: spin t = bit t
    __shared__ short    hbuf[2][40];   // h: [batch][unit], row stride 80 B
    __shared__ float2   Sbuf[256][2];  // raw head logits (S0,S1) per (t,batch)

    // ---- stage spins as packed bits (in-wave; DS in-order, no barrier) ----
    {
        const int bl = lane >> 5;
        const int c8 = (lane & 31) * 8;
        const int4* src = reinterpret_cast<const int4*>(x + (b0 + bl) * 256 + c8);
        const int4 v0 = src[0], v1 = src[1];
        const unsigned bv =
            (v0.x & 1) | ((v0.y & 1) << 1) | ((v0.z & 1) << 2) | ((v0.w & 1) << 3) |
            ((v1.x & 1) << 4) | ((v1.y & 1) << 5) | ((v1.z & 1) << 6) | ((v1.w & 1) << 7);
        reinterpret_cast<char*>(spinw)[bl * 32 + (lane & 31)] = (char)bv;
    }

    // ---- weight A-frags: tile 2q+sx covers gate q, units 16sx..16sx+15.
    // A[row n][k=8oct+jj] = gs(q) * Wh[unit 8oct+jj][gate-col 32q+16sx+n].
    bf16x8 wfrag[8];
#pragma unroll
    for (int q = 0; q < 4; ++q) {
        const float gs = (q == 2) ? (2.f * LOG2E) : -LOG2E;
#pragma unroll
        for (int sx = 0; sx < 2; ++sx)
#pragma unroll
            for (int jj = 0; jj < 8; ++jj)
                wfrag[2 * q + sx][jj] =
                    (short)f2bf(gs * Wh[(8 * oct + jj) * 128 + 32 * q + 16 * sx + n]);
    }
    bf16x8 wofrag;   // head: Wo^T in rows 0,1
#pragma unroll
    for (int jj = 0; jj < 8; ++jj)
        wofrag[jj] = (n < 2) ? (short)f2bf(Wo[(8 * oct + jj) * 2 + n]) : (short)0;

    // ---- this lane's cell + scaled biases ----
    const int u = 4 * oct + (j & 3) + 16 * (j >> 2);
    float bv0[4], bvd[4];
#pragma unroll
    for (int q = 0; q < 4; ++q) {
        const float gs = (q == 2) ? (2.f * LOG2E) : -LOG2E;
        const int c0 = 32 * q + u;
        bv0[q] = gs * (bh[c0] + Wi[c0]);
        bvd[q] = gs * (Wi[128 + c0] - Wi[c0]);
    }
    const float bo0 = bo[0], bo1 = bo[1];

    const bool j1 = (j & 1) != 0;
    const bool j2 = (j & 2) != 0;
    const bool j4 = (j & 4) != 0;

    // ---- peel t=0: input zeros, h=c=0 -> gates = bh; state c' = 2L*c ----
    float cp = TWOL * (fsig(bh[u]) * ftanh_(bh[64 + u]));
    hbuf[m][u] = (short)f2bf(fsig(bh[96 + u]) * ftanh_(cp * (1.f / TWOL)));

    const f32x4 zero4 = { 0.f, 0.f, 0.f, 0.f };

    // ---- main loop: t = 32k+1+i runs 1..256. Step 256 is dead work except
    // its hfrag (= h_255) feeds the step-255 head. Spin_{t-1} = word k bit i.
    for (int k = 0; k < 8; ++k) {
        const unsigned cur = spinw[m][k];
#pragma unroll
        for (int i = 0; i < 32; ++i) {
            const float spf = (float)((cur >> i) & 1u);

            // B-frag: h_{t-1} of my batch (same-wave write earlier -> in-order)
            const bf16x8 hfrag = *reinterpret_cast<const bf16x8*>(&hbuf[m][8 * oct]);

            f32x4 acc[8];
#pragma unroll
            for (int tt = 0; tt < 8; ++tt)
                acc[tt] = __builtin_amdgcn_mfma_f32_16x16x32_bf16(wfrag[tt], hfrag, zero4, 0, 0, 0);
            const f32x4 hacc =
                __builtin_amdgcn_mfma_f32_16x16x32_bf16(wofrag, hfrag, zero4, 0, 0, 0);

            // head logits of step t-1 = 32k+i (lane 0 -> batch 0, lane 1 -> batch 1)
            if (lane < 2) Sbuf[32 * k + i][lane] = make_float2(hacc[0], hacc[1]);

            // extract my 4 gates: tile 2q + (j>>2), reg (j&3); then add bias
            float g[4];
#pragma unroll
            for (int q = 0; q < 4; ++q) {
                const f32x4 a = acc[2 * q], b = acc[2 * q + 1];
                const float a01 = j1 ? a[1] : a[0];
                const float a23 = j1 ? a[3] : a[2];
                const float av  = j2 ? a23 : a01;
                const float b01 = j1 ? b[1] : b[0];
                const float b23 = j1 ? b[3] : b[2];
                const float bvv = j2 ? b23 : b01;
                g[q] = (j4 ? bvv : av) + fmaf(spf, bvd[q], bv0[q]);
            }

            // cell update: e_i=e^{-i}, e_f=e^{-f}, e_g=e^{2g}, e_o=e^{-o}
            {
                const float ei = fexp2(g[0]), ef = fexp2(g[1]);
                const float eg = fexp2(g[2]), eo = fexp2(g[3]);
                const float P  = (1.f + ei) * (1.f + eg);
                const float Q  = 1.f + ef;
                const float E  = fmaf(eg, TWOL, -TWOL);     // 2L*(eg-1)
                const float R  = frcp(P * Q);
                const float gf   = P * R;                    // 1/(1+ef)
                const float igtp = E * Q * R;                // 2L*sig(i)*tanh(g)
                cp = fmaf(gf, cp, igtp);
                const float ec = fexp2(cp);                  // e^{2c}
                const float h  = (ec - 1.f) * frcp((1.f + eo) * (1.f + ec));
                hbuf[m][u] = (short)f2bf(h);
            }
        }
    }

    // ---- post phase: ELU + log-softmax + sum over t (in-wave) ----
    {
        const int m2    = lane & 1;
        const int chunk = lane >> 1;   // 32 chunks of 8 steps
        const unsigned sb =
            (unsigned char)reinterpret_cast<const char*>(spinw)[m2 * 32 + chunk];
        float lp = 0.f;
#pragma unroll
        for (int i = 0; i < 8; ++i) {
            const int t = chunk * 8 + i;
            const float2 sv = Sbuf[t][m2];
            const int sp = (sb >> i) & 1u;
            const float o0 = felu(sv.x + bo0);
            const float o1 = felu(sv.y + bo1);
            const float mx = fmaxf(o0, o1), mn = fminf(o0, o1);
            const float lse = mx + LN2 * flog2(1.f + fexp2(LOG2E * (mn - mx)));
            lp += (sp ? o1 : o0) - lse;
        }
        lp += __shfl_xor(lp, 2, 64);
        lp += __shfl_xor(lp, 4, 64);
        lp += __shfl_xor(lp, 8, 64);
        lp += __shfl_xor(lp, 16, 64);
        lp += __shfl_xor(lp, 32, 64);
        if (lane < 2) out[b0 + lane] = 0.5f * lp;
    }
}

extern "C" void kernel_launch(void* const* d_in, const int* in_sizes, int n_in,
                              void* d_out, int out_size, void* d_ws, size_t ws_size,
                              hipStream_t stream) {
    const int*   x  = (const int*)d_in[0];
    const float* Wi = (const float*)d_in[1];
    const float* Wh = (const float*)d_in[2];
    const float* bh = (const float*)d_in[3];
    const float* Wo = (const float*)d_in[4];
    const float* bo = (const float*)d_in[5];
    float* out = (float*)d_out;

    lstm_wpriv<<<dim3(Bsz / 2), dim3(64), 0, stream>>>(x, Wi, Wh, bh, Wo, bo, out);
}